// Round 7
// baseline (285.514 us; speedup 1.0000x reference)
//
#include <hip/hip_runtime.h>
#include <hip/hip_bf16.h>
#include <math.h>

#define B_ 2
#define T_ 2048
#define C_ 1024
#define H_ 16
#define G_ 4
#define DQK_ 64
#define DV_ 128
#define NQKV 1792   // H*DQK + G*DQK + G*DV
#define KS2 2048    // compact split storage: [hi | lo]
// Logical GEMM K = 3072 tiles 0..95: s0=hi·hi (0..31), s1=lo·hi (32..63),
// s2=hi·lo (64..95). Column remap: ktA = kt<64?kt:kt-64; ktB = kt<32?kt:kt-32.
// Operand rows are chunk-XOR-swizzled: 8-elem chunk c of row r stored at
// physical chunk c ^ ((r>>1)&3)  -> fragment ds_read_b128 is bank-conflict-free.

typedef __attribute__((ext_vector_type(8))) short short8;
typedef __attribute__((ext_vector_type(4))) short short4v;
typedef __attribute__((ext_vector_type(4))) float f32x4;
typedef unsigned short ushort_t;

__device__ inline ushort_t f2bf(float f) {
  union { float f; unsigned int u; } v; v.f = f;
  unsigned int r = (v.u + 0x7FFFu + ((v.u >> 16) & 1u)) >> 16;  // RNE
  return (ushort_t)r;
}
__device__ inline float bf2f(ushort_t h) {
  union { unsigned int u; float f; } v; v.u = ((unsigned int)h) << 16;
  return v.f;
}

#define GLD_LDS16(g, l)                                              \
  __builtin_amdgcn_global_load_lds(                                  \
      (const __attribute__((address_space(1))) void*)(g),            \
      (__attribute__((address_space(3))) void*)(l), 16, 0, 0)

// ---------------------------------------------------------------------------
// Kernel 0a: split-cast x -> xb[4096][2048] bf16 = [x_hi | x_lo], swizzled.
// One thread per (m, 8-elem chunk).
// ---------------------------------------------------------------------------
__global__ __launch_bounds__(256) void cast_x(
    const float* __restrict__ x, ushort_t* __restrict__ xb) {
  int idx = blockIdx.x * 256 + threadIdx.x;   // 4096*128 = 524288
  int m = idx >> 7;
  int c8 = idx & 127;                          // chunk of 8 within 1024
  const float* src = &x[(size_t)m * 1024 + c8 * 8];
  float4 v0 = *(const float4*)&src[0];
  float4 v1 = *(const float4*)&src[4];
  float f[8] = {v0.x, v0.y, v0.z, v0.w, v1.x, v1.y, v1.z, v1.w};
  short8 hv, lv;
#pragma unroll
  for (int c = 0; c < 8; c++) {
    ushort_t h = f2bf(f[c]);
    hv[c] = (short)h;
    lv[c] = (short)f2bf(f[c] - bf2f(h));
  }
  int key = (m >> 1) & 3;
  int phys = (c8 & ~3) * 8 + ((c8 & 3) ^ key) * 8;
  ushort_t* row = xb + (size_t)m * KS2;
  *(short8*)&row[phys] = hv;
  *(short8*)&row[1024 + phys] = lv;
}

// ---------------------------------------------------------------------------
// Kernel 0b: transpose+split-cast W -> wt[1792][2048] bf16 = [w_hi | w_lo],
// swizzled with key (n>>1)&3.
// ---------------------------------------------------------------------------
__global__ __launch_bounds__(256) void cast_w(
    const float* __restrict__ Wq, const float* __restrict__ Wk,
    const float* __restrict__ Wv, ushort_t* __restrict__ wt) {
  __shared__ float tile[64][65];
  const int n0 = blockIdx.x * 64;
  const int k0 = blockIdx.y * 64;
  const int tid = threadIdx.x;

  const float* Wp; int ldw, noff;
  if (n0 < 1024)      { Wp = Wq; ldw = 1024; noff = n0; }
  else if (n0 < 1280) { Wp = Wk; ldw = 256;  noff = n0 - 1024; }
  else                { Wp = Wv; ldw = 512;  noff = n0 - 1280; }

#pragma unroll
  for (int it = 0; it < 4; it++) {
    int fi = it * 256 + tid;
    int kk = fi >> 4;
    int nc = (fi & 15) * 4;
    float4 v = *(const float4*)&Wp[(size_t)(k0 + kk) * ldw + noff + nc];
    tile[nc + 0][kk] = v.x; tile[nc + 1][kk] = v.y;
    tile[nc + 2][kk] = v.z; tile[nc + 3][kk] = v.w;
  }
  __syncthreads();
  int nn = tid >> 2, seg = tid & 3;   // 16 k per thread (2 chunks of 8)
  int n = n0 + nn;
  int key = (n >> 1) & 3;
  ushort_t* row = wt + (size_t)n * KS2;
#pragma unroll
  for (int j = 0; j < 2; j++) {
    short8 hv, lv;
#pragma unroll
    for (int u = 0; u < 8; u++) {
      float f = tile[nn][seg * 16 + j * 8 + u];
      ushort_t h = f2bf(f);
      hv[u] = (short)h;
      lv[u] = (short)f2bf(f - bf2f(h));
    }
    int c8 = (k0 >> 3) + seg * 2 + j;
    int phys = (c8 & ~3) * 8 + ((c8 & 3) ^ key) * 8;
    *(short8*)&row[phys] = hv;
    *(short8*)&row[1024 + phys] = lv;
  }
}

// ---------------------------------------------------------------------------
// Kernel 1: bf16-MFMA QKV GEMM.  Single-barrier K-loop with async LDS
// double-buffer: prefetch tile k+1 via global_load_lds into the other buffer
// while MFMAing tile k; one __syncthreads per iter drains both.
// ---------------------------------------------------------------------------
__global__ __launch_bounds__(256) void gemm_qkv_mfma(
    const ushort_t* __restrict__ xb, const ushort_t* __restrict__ wt,
    float* __restrict__ qkv) {
  __shared__ ushort_t At[2][128 * 32];
  __shared__ ushort_t Bt[2][128 * 32];
  const int tid = threadIdx.x;
  const int wave = tid >> 6, lane = tid & 63;
  const int quad = lane >> 4, l16 = lane & 15;
  const int m0 = blockIdx.y * 128, n0 = blockIdx.x * 128;
  const int wm = (wave & 1) * 64, wn = (wave >> 1) * 64;
  const int physq = (quad ^ ((l16 >> 1) & 3)) * 8;   // de-swizzle read column

  f32x4 acc[4][4];
#pragma unroll
  for (int i = 0; i < 4; i++)
#pragma unroll
    for (int j = 0; j < 4; j++) acc[i][j] = (f32x4){0.f, 0.f, 0.f, 0.f};

  const int rA = wave * 32 + (lane >> 2);
  const int cA = (lane & 3) * 8;
  const ushort_t* gA = xb + (size_t)(m0 + rA) * KS2 + cA;
  const ushort_t* gB = wt + (size_t)(n0 + rA) * KS2 + cA;

#define STAGE(b, ca, cb)                                                 \
  do {                                                                   \
    GLD_LDS16(gA + (ca), &At[b][(wave * 32) * 32]);                      \
    GLD_LDS16(gA + (ca) + 16 * KS2, &At[b][(wave * 32 + 16) * 32]);      \
    GLD_LDS16(gB + (cb), &Bt[b][(wave * 32) * 32]);                      \
    GLD_LDS16(gB + (cb) + 16 * KS2, &Bt[b][(wave * 32 + 16) * 32]);      \
  } while (0)

  STAGE(0, 0, 0);
  __syncthreads();

  for (int kt = 0; kt < 96; kt++) {
    const int buf = kt & 1;
    const int kn = kt + 1;
    if (kn < 96) {
      const int ca = (kn < 64 ? kn : kn - 64) * 32;
      const int cb = (kn < 32 ? kn : kn - 32) * 32;
      STAGE(buf ^ 1, ca, cb);   // in flight during this iter's MFMAs
    }
    short8 af[4], bf[4];
#pragma unroll
    for (int i = 0; i < 4; i++)
      af[i] = *(const short8*)&At[buf][(wm + 16 * i + l16) * 32 + physq];
#pragma unroll
    for (int j = 0; j < 4; j++)
      bf[j] = *(const short8*)&Bt[buf][(wn + 16 * j + l16) * 32 + physq];
#pragma unroll
    for (int i = 0; i < 4; i++)
#pragma unroll
      for (int j = 0; j < 4; j++)
        acc[i][j] = __builtin_amdgcn_mfma_f32_16x16x32_bf16(
            af[i], bf[j], acc[i][j], 0, 0, 0);
    __syncthreads();   // drains prefetch (covered by MFMA) + read waits
  }
#undef STAGE

#pragma unroll
  for (int i = 0; i < 4; i++) {
    int m = m0 + wm + 16 * i + quad * 4;
#pragma unroll
    for (int j = 0; j < 4; j++) {
      int n = n0 + wn + 16 * j + l16;
#pragma unroll
      for (int r = 0; r < 4; r++)
        qkv[(size_t)(m + r) * NQKV + n] = acc[i][j][r];
    }
  }
}

// ---------------------------------------------------------------------------
// Kernel 2: RoPE + qk-norm -> unit-norm bf16 q,k in MFMA-fragment layouts.
// ---------------------------------------------------------------------------
__global__ __launch_bounds__(256) void rope_norm(
    const float* __restrict__ qkv,
    ushort_t* __restrict__ qf, ushort_t* __restrict__ kf) {
  const int NQ = B_ * T_ * H_;
  int vec = blockIdx.x * 4 + (threadIdx.x >> 6);
  int d = threadIdx.x & 63;

  size_t src; int t, b, isq; ushort_t* dstbase;
  if (vec < NQ) {
    int h = vec % H_; int bt = vec / H_;
    t = bt % T_; b = bt / T_;
    src = (size_t)bt * NQKV + h * 64 + d;
    dstbase = qf + (size_t)(b * 16 + h) * 131072;
    isq = 1;
  } else {
    int vk = vec - NQ;
    int g = vk % G_; int bt = vk / G_;
    t = bt % T_; b = bt / T_;
    src = (size_t)bt * NQKV + 1024 + g * 64 + d;
    dstbase = kf + (size_t)(b * 4 + g) * 131072;
    isq = 0;
  }
  float val = qkv[src];
  int i = d & 31;
  float inv = exp2f(-(float)i * 0.4152410118074239f);  // log2(10000)/32
  float ang = (float)t * inv;
  float sn, cs;
  __sincosf(ang, &sn, &cs);
  float partner = __shfl(val, d ^ 32, 64);
  float r = (d < 32) ? (val * cs - partner * sn) : (val * cs + partner * sn);
  float ss = r * r;
#pragma unroll
  for (int off = 32; off; off >>= 1) ss += __shfl_xor(ss, off, 64);
  r *= 1.0f / (sqrtf(ss) + 1e-6f);

  int kt = t >> 6, tt = t & 63;
  int l16v = tt & 15;
  int ks = d >> 5, quad = (d >> 3) & 3, j = d & 7;
  size_t off2;
  if (isq) {
    int wavei = tt >> 4;
    off2 = ((size_t)(kt * 8 + wavei * 2 + ks) * 4 + quad) * 128 + l16v * 8 + j;
  } else {
    int nt = tt >> 4;
    off2 = ((size_t)(kt * 8 + ks * 4 + nt) * 4 + quad) * 128 + l16v * 8 + j;
  }
  dstbase[off2] = f2bf(r);
}

// ---------------------------------------------------------------------------
// Kernel 2b: V scatter + bf16 cast into PV B-fragment layout.
// ---------------------------------------------------------------------------
__global__ __launch_bounds__(256) void vscatter(
    const float* __restrict__ qkv, ushort_t* __restrict__ vf) {
  int idx = blockIdx.x * 256 + threadIdx.x;   // 2,097,152
  int dv = idx & 127;
  int t = (idx >> 7) & 2047;
  int g = (idx >> 18) & 3;
  int b = idx >> 20;
  size_t src = (size_t)(b * T_ + t) * NQKV + 1280 + g * 128 + dv;
  float v = qkv[src];
  int kt = t >> 6, ks = (t >> 5) & 1, quad = (t >> 3) & 3, j = t & 7;
  int nv = dv >> 4, l16v = dv & 15;
  size_t off = ((size_t)(kt * 16 + ks * 8 + nv) * 4 + quad) * 128 + l16v * 8 + j;
  vf[(size_t)(b * 4 + g) * 262144 + off] = f2bf(v);
}

// ---------------------------------------------------------------------------
// Kernel 3: bf16-MFMA causal flash attention, fixed-max softmax (m = gsc),
// l via ones-column MFMA.
// ---------------------------------------------------------------------------
__global__ __launch_bounds__(256) void attn(
    const ushort_t* __restrict__ qf, const ushort_t* __restrict__ kf,
    const ushort_t* __restrict__ vf, const float* __restrict__ lobo,
    const float* __restrict__ qknf, float* __restrict__ y) {
  const int f = blockIdx.x;
  const int b = f >> 9;
  const int h = (f >> 5) & 15;
  const int qt = ((f & 31) + 8 * (f >> 8)) & 31;
  const int g = h >> 2;

  __shared__ ushort_t Ks[8 * 512];
  __shared__ ushort_t Vs[16 * 512];
  __shared__ ushort_t Vones[512];
  __shared__ ushort_t Ps[64 * 68];

  const int tid = threadIdx.x;
  const int wave = tid >> 6, lane = tid & 63;
  const int quad = lane >> 4, l16 = lane & 15;

  if (tid < 64) {
    ushort_t vv = ((tid & 15) == 0) ? (ushort_t)0x3F80 : (ushort_t)0;
#pragma unroll
    for (int u = 0; u < 8; u++) Vones[tid * 8 + u] = vv;
  }

  const ushort_t* qb =
      qf + ((size_t)((b * 16 + h) * 32 + qt) * 8 + wave * 2) * 512;
  short8 aq0 = *(const short8*)&qb[lane * 8];
  short8 aq1 = *(const short8*)&qb[512 + lane * 8];

  f32x4 o[9];
#pragma unroll
  for (int nv = 0; nv < 9; nv++) o[nv] = (f32x4){0.f, 0.f, 0.f, 0.f};

  const float gsc = qknf[0];
  const float sinkp = __expf(lobo[h] - gsc);

  const ushort_t* kt0 = kf + (size_t)(b * 4 + g) * 131072;
  const ushort_t* vt0 = vf + (size_t)(b * 4 + g) * 262144;

  for (int kt = 0; kt <= qt; kt++) {
    __syncthreads();
    const ushort_t* kg = kt0 + (size_t)kt * 4096;
    const ushort_t* vg = vt0 + (size_t)kt * 8192;
    GLD_LDS16(kg + (wave * 2 + 0) * 512 + lane * 8, &Ks[(wave * 2 + 0) * 512]);
    GLD_LDS16(kg + (wave * 2 + 1) * 512 + lane * 8, &Ks[(wave * 2 + 1) * 512]);
#pragma unroll
    for (int u = 0; u < 4; u++)
      GLD_LDS16(vg + (wave * 4 + u) * 512 + lane * 8,
                &Vs[(wave * 4 + u) * 512]);
    __syncthreads();

    f32x4 s[4];
#pragma unroll
    for (int nt = 0; nt < 4; nt++) s[nt] = (f32x4){0.f, 0.f, 0.f, 0.f};
#pragma unroll
    for (int nt = 0; nt < 4; nt++) {
      short8 bk = *(const short8*)&Ks[nt * 512 + lane * 8];
      s[nt] = __builtin_amdgcn_mfma_f32_16x16x32_bf16(aq0, bk, s[nt], 0, 0, 0);
    }
#pragma unroll
    for (int nt = 0; nt < 4; nt++) {
      short8 bk = *(const short8*)&Ks[(4 + nt) * 512 + lane * 8];
      s[nt] = __builtin_amdgcn_mfma_f32_16x16x32_bf16(aq1, bk, s[nt], 0, 0, 0);
    }

    const bool diag = (kt == qt);
#pragma unroll
    for (int nt = 0; nt < 4; nt++)
#pragma unroll
      for (int r = 0; r < 4; r++) {
        float p = __expf((s[nt][r] - 1.0f) * gsc);
        if (diag && (nt * 16 + l16) > (wave * 16 + quad * 4 + r)) p = 0.f;
        Ps[(wave * 16 + quad * 4 + r) * 68 + nt * 16 + l16] = f2bf(p);
      }

    short8 ap0 = *(const short8*)&Ps[(wave * 16 + l16) * 68 + quad * 8];
    short8 ap1 = *(const short8*)&Ps[(wave * 16 + l16) * 68 + 32 + quad * 8];
#pragma unroll
    for (int nv = 0; nv < 8; nv++) {
      short8 bv = *(const short8*)&Vs[nv * 512 + lane * 8];
      o[nv] = __builtin_amdgcn_mfma_f32_16x16x32_bf16(ap0, bv, o[nv], 0, 0, 0);
    }
    {
      short8 bo = *(const short8*)&Vones[lane * 8];
      o[8] = __builtin_amdgcn_mfma_f32_16x16x32_bf16(ap0, bo, o[8], 0, 0, 0);
      o[8] = __builtin_amdgcn_mfma_f32_16x16x32_bf16(ap1, bo, o[8], 0, 0, 0);
    }
#pragma unroll
    for (int nv = 0; nv < 8; nv++) {
      short8 bv = *(const short8*)&Vs[(8 + nv) * 512 + lane * 8];
      o[nv] = __builtin_amdgcn_mfma_f32_16x16x32_bf16(ap1, bv, o[nv], 0, 0, 0);
    }
  }

#pragma unroll
  for (int r = 0; r < 4; r++) {
    float lm = __shfl(o[8][r], lane & 48, 64);
    float invl = 1.0f / (lm + sinkp);
    size_t row = (size_t)b * T_ + qt * 64 + wave * 16 + quad * 4 + r;
#pragma unroll
    for (int nv = 0; nv < 8; nv++)
      atomicAdd(&y[row * 128 + nv * 16 + l16], o[nv][r] * invl);
  }
}

// ---------------------------------------------------------------------------
// Kernel 4: out = y[B*T,128] @ Wproj[128,1024]  (fp32).
// ---------------------------------------------------------------------------
__global__ __launch_bounds__(256) void out_proj(
    const float* __restrict__ y, const float* __restrict__ Wproj,
    float* __restrict__ out) {
  __shared__ float ylds[4][128];
  const int m0 = blockIdx.x * 4;
  const int tid = threadIdx.x;
  *(float2*)&((float*)ylds)[tid * 2] = *(const float2*)&y[(size_t)m0 * 128 + tid * 2];
  __syncthreads();
  float acc[4][4];
#pragma unroll
  for (int i = 0; i < 4; i++)
#pragma unroll
    for (int j = 0; j < 4; j++) acc[i][j] = 0.0f;
  for (int k = 0; k < 128; k++) {
    float w[4];
#pragma unroll
    for (int j = 0; j < 4; j++) w[j] = Wproj[(size_t)k * 1024 + tid + 256 * j];
#pragma unroll
    for (int i = 0; i < 4; i++) {
      float yv = ylds[i][k];
#pragma unroll
      for (int j = 0; j < 4; j++) acc[i][j] += yv * w[j];
    }
  }
#pragma unroll
  for (int i = 0; i < 4; i++)
#pragma unroll
    for (int j = 0; j < 4; j++)
      out[(size_t)(m0 + i) * 1024 + tid + 256 * j] = acc[i][j];
}

// ---------------------------------------------------------------------------
extern "C" void kernel_launch(void* const* d_in, const int* in_sizes, int n_in,
                              void* d_out, int out_size, void* d_ws, size_t ws_size,
                              hipStream_t stream) {
  const float* x     = (const float*)d_in[0];
  const float* Wq    = (const float*)d_in[2];
  const float* Wk    = (const float*)d_in[3];
  const float* Wv    = (const float*)d_in[4];
  const float* Wproj = (const float*)d_in[5];
  const float* lobo  = (const float*)d_in[6];
  const float* qknf  = (const float*)d_in[7];
  float* out = (float*)d_out;

  // ws: [qkv f32 29.4MB | xb bf16 16.8MB | wt bf16 7.3MB]; qf/kf/vf/y alias xb.
  float* qkv = (float*)d_ws;                                    // 7,340,032 f32
  ushort_t* xb = (ushort_t*)(qkv + (size_t)B_ * T_ * NQKV);     // 8,388,608 bf16
  ushort_t* wt = xb + (size_t)B_ * T_ * KS2;                    // 3,670,016 bf16
  ushort_t* qf = xb;                                            // 4,194,304 bf16
  ushort_t* kf = qf + (size_t)B_ * H_ * T_ * 64;                // 1,048,576 bf16
  ushort_t* vf = kf + (size_t)B_ * G_ * T_ * 64;                // 2,097,152 bf16
  float* y = (float*)(vf + (size_t)B_ * G_ * T_ * 128);         //   524,288 f32

  cast_x<<<(B_ * T_ * 128) / 256, 256, 0, stream>>>(x, xb);
  dim3 gw(NQKV / 64, C_ / 64);
  cast_w<<<gw, 256, 0, stream>>>(Wq, Wk, Wv, wt);

  dim3 gg(NQKV / 128, (B_ * T_) / 128);
  gemm_qkv_mfma<<<gg, 256, 0, stream>>>(xb, wt, qkv);

  int nvec = B_ * T_ * H_ + B_ * T_ * G_;   // 81920
  rope_norm<<<nvec / 4, 256, 0, stream>>>(qkv, qf, kf);

  vscatter<<<(B_ * G_ * T_ * DV_) / 256, 256, 0, stream>>>(qkv, vf);

  (void)hipMemsetAsync(y, 0, (size_t)B_ * T_ * 128 * sizeof(float), stream);

  attn<<<B_ * H_ * (T_ / 64), 256, 0, stream>>>(qf, kf, vf, lobo, qknf, y);

  out_proj<<<(B_ * T_) / 4, 256, 0, stream>>>(y, Wproj, out);
}